// Round 5
// baseline (90622.803 us; speedup 1.0000x reference)
//
#include <hip/hip_runtime.h>
#include <math.h>

// Problem constants
#define B 256
#define Hh 512
#define S 200
#define T 200
#define VOC 512
#define G3 1536
#define PAD 36

// fp64 helpers: inner-product math in double, tensor boundaries quantized fp32.
struct d4 { double x, y, z, w; };
__device__ __forceinline__ d4 tod4(const float4 a) {
    d4 r; r.x = a.x; r.y = a.y; r.z = a.z; r.w = a.w; return r;
}
__device__ __forceinline__ double dotd(const d4& a, const d4& b) {
    return a.x * b.x + a.y * b.y + a.z * b.z + a.w * b.w;
}
__device__ __forceinline__ double sigd(double x) { return 1.0 / (1.0 + exp(-x)); }

typedef double f64x4 __attribute__((ext_vector_type(4)));

__device__ __forceinline__ unsigned long long dbits(double v) {
    return (unsigned long long)__double_as_longlong(v);
}

// ---------------------------------------------------------------------------
// Device-scope grid barrier (sense-reversing generation counter).
// All blocks of the grid MUST call it the same number of times.
// bar[0] = arrival counter, bar[1] = generation. Zeroed host-side.
// Release: __threadfence before arrival. Acquire: __threadfence after wake.
// ---------------------------------------------------------------------------
__device__ __forceinline__ void gridbar(int* bar, int nblk)
{
    __syncthreads();
    if (threadIdx.x == 0) {
        __threadfence();                       // release phase writes
        const int gen = atomicAdd(bar + 1, 0); // read generation BEFORE arrive
        if (atomicAdd(bar, 1) == nblk - 1) {
            atomicExch(bar, 0);                // reset for next barrier
            __threadfence();
            atomicAdd(bar + 1, 1);             // open the gate
        } else {
            while (atomicAdd(bar + 1, 0) == gen)
                __builtin_amdgcn_s_sleep(16);
        }
        __threadfence();                       // acquire remote writes
    }
    __syncthreads();
}

// ---------------------------------------------------------------------------
// Self-calibration for v_mfma_f64_16x16x4f64 (round-3/4 proven, absmax 0.0).
// ---------------------------------------------------------------------------
__device__ __forceinline__ void calib(int lane, int& am, int& ak, int* rowd)
{
    f64x4 z = { 0.0, 0.0, 0.0, 0.0 };
    f64x4 va = __builtin_amdgcn_mfma_f64_16x16x4f64(
        (double)(1ULL << lane), 1.0, z, 0, 0, 0);
    const unsigned long long MM = 0xFFFFFFFFFFFFFULL;
    const unsigned long long M0 = (1ULL << 36) | (1ULL << 20) | (1ULL << 4);
    const int fam0 = __all(
        ((dbits(va[0]) & MM) == M0) && ((dbits(va[1]) & MM) == M0) &&
        ((dbits(va[2]) & MM) == M0) && ((dbits(va[3]) & MM) == M0));
    am = fam0 ? (lane & 15) : (lane >> 2);
    ak = fam0 ? (lane >> 4) : (lane & 3);
    f64x4 vr = __builtin_amdgcn_mfma_f64_16x16x4f64(
        (double)(1ULL << am), 1.0, z, 0, 0, 0);
#pragma unroll
    for (int d = 0; d < 4; ++d)
        rowd[d] = (int)((dbits(vr[d]) >> 52) & 0x7ff) - 1025;
}

// ---------------------------------------------------------------------------
// Table-precompute GEMM (proven).
// ---------------------------------------------------------------------------
__global__ __launch_bounds__(256) void gemm_at(
    const float* __restrict__ A,
    const float* __restrict__ W, int ldw, int woff,
    const float* __restrict__ bias,
    float* __restrict__ C, int ldc)
{
    __shared__ float As[32][PAD];
    __shared__ float Ws[32][PAD];
    const int tid = threadIdx.x;
    const int tx = tid & 15, ty = tid >> 4;
    const int j0 = blockIdx.x * 32, m0 = blockIdx.y * 32;
    const int lr = tid >> 3, lc = (tid & 7) * 4;

    double acc00 = 0.0, acc01 = 0.0, acc10 = 0.0, acc11 = 0.0;

    for (int k0 = 0; k0 < 512; k0 += 32) {
        float4 av = *(const float4*)(A + (size_t)(m0 + lr) * 512 + k0 + lc);
        float4 wv = *(const float4*)(W + (size_t)(j0 + lr) * ldw + woff + k0 + lc);
        __syncthreads();
        *(float4*)&As[lr][lc] = av;
        *(float4*)&Ws[lr][lc] = wv;
        __syncthreads();
#pragma unroll
        for (int kk = 0; kk < 32; kk += 4) {
            d4 a0 = tod4(*(const float4*)&As[ty][kk]);
            d4 a1 = tod4(*(const float4*)&As[ty + 16][kk]);
            d4 b0 = tod4(*(const float4*)&Ws[tx][kk]);
            d4 b1 = tod4(*(const float4*)&Ws[tx + 16][kk]);
            acc00 += dotd(a0, b0);
            acc01 += dotd(a0, b1);
            acc10 += dotd(a1, b0);
            acc11 += dotd(a1, b1);
        }
    }
    const int ms[2] = { m0 + ty, m0 + ty + 16 };
    const int js[2] = { j0 + tx, j0 + tx + 16 };
    double accs[2][2] = { { acc00, acc01 }, { acc10, acc11 } };
#pragma unroll
    for (int mi = 0; mi < 2; ++mi)
#pragma unroll
        for (int ji = 0; ji < 2; ++ji) {
            int m = ms[mi], j = js[ji];
            C[(size_t)m * ldc + j] = (float)(accs[mi][ji] + (double)bias[j]);
        }
}

// ---------------------------------------------------------------------------
// Persistent encoder: ONE launch, 256 blocks x 512 thr (R0 enc_step occupancy,
// 8 waves/CU; __launch_bounds__(512,4) guarantees >=2 blocks/CU capacity so
// all 256 blocks are co-resident under any packing). Per step s the block
// executes the EXACT R0 enc_step body (bitwise-identical chains/epilogue),
// then a grid barrier. h ping-pongs between h0/h1 in-kernel.
// ---------------------------------------------------------------------------
__global__ __launch_bounds__(512, 4) void enc_persist(
    float* __restrict__ h0buf, float* __restrict__ h1buf,
    const float* __restrict__ gi_tab, const int* __restrict__ iseq,
    const int* __restrict__ ilen, const float* __restrict__ Whh,
    const float* __restrict__ bhh, float* __restrict__ enc_out,
    int* __restrict__ bar)
{
    __shared__ float Hs[32][68];
    __shared__ float Ws[48][68];
    const int tid = threadIdx.x;
    const int blk = blockIdx.x;
    const int bx = blk & 31, by = blk >> 5;
    const int j_l = tid & 15, b_l = tid >> 4;
    const int j0 = bx * 16, b0 = by * 32;
    const int j = j0 + j_l, b = b0 + b_l;

    int ml = 0;
    for (int i = 0; i < 32; ++i) ml = max(ml, ilen[b0 + i]);

    for (int s = 0; s < S; ++s) {
        const float* h_in = (s & 1) ? h1buf : h0buf;
        float* h_out = (s & 1) ? h0buf : h1buf;

        if (s >= ml) {   // tile past its lengths: copy + zero (R0 path)
            h_out[(size_t)b * 512 + j] = h_in[(size_t)b * 512 + j];
            enc_out[((size_t)s * B + b) * 512 + j] = 0.f;
        } else {
            double ar = 0.0, az = 0.0, an = 0.0;
            for (int kt = 0; kt < 512; kt += 64) {
                __syncthreads();
                {
                    int row = tid >> 4, c4 = (tid & 15) * 4;
                    *(float4*)&Hs[row][c4] =
                        *(const float4*)(h_in + (size_t)(b0 + row) * 512 + kt + c4);
                    for (int idx = tid; idx < 768; idx += 512) {
                        int r = idx >> 4, cc = (idx & 15) * 4;
                        int g = r >> 4, jj = r & 15;
                        *(float4*)&Ws[r][cc] =
                            *(const float4*)(Whh + (size_t)(g * 512 + j0 + jj) * 512 + kt + cc);
                    }
                }
                __syncthreads();
#pragma unroll
                for (int kk = 0; kk < 64; kk += 4) {
                    d4 hv = tod4(*(const float4*)&Hs[b_l][kk]);
                    ar += dotd(hv, tod4(*(const float4*)&Ws[j_l][kk]));
                    az += dotd(hv, tod4(*(const float4*)&Ws[16 + j_l][kk]));
                    an += dotd(hv, tod4(*(const float4*)&Ws[32 + j_l][kk]));
                }
            }

            float hold = h_in[(size_t)b * 512 + j];
            float hnew = hold;
            if (s < ilen[b]) {
                int tok = iseq[s * B + b];
                const float* gi = gi_tab + (size_t)tok * G3;
                double r = sigd((double)gi[j] + ar + (double)bhh[j]);
                double z = sigd((double)gi[512 + j] + az + (double)bhh[512 + j]);
                double n = tanh((double)gi[1024 + j] + r * (an + (double)bhh[1024 + j]));
                hnew = (float)((1.0 - z) * n + z * (double)hold);
                enc_out[((size_t)s * B + b) * 512 + j] = hnew;
            } else {
                enc_out[((size_t)s * B + b) * 512 + j] = 0.f;
            }
            h_out[(size_t)b * 512 + j] = hnew;
        }

        gridbar(bar, 256);
    }
}

// ---------------------------------------------------------------------------
// Persistent decoder: ONE launch, 640 blocks x 256 thr (>=3 blocks/CU by
// __launch_bounds__(256,3) => all co-resident). Per step t:
//   Phase B' (R4 dec_att partition, proven):
//     blocks [0,256):   attention + ctx + x for b=bid            [t<T]
//     blocks [256,512): softmax/argmax/nll of lgbB -> step t-2   [t>=2]
//     blocks [512,640): MFMA logits lgbA = h_t @ out_W^T + out_b [1<=t<=T]
//   barrier
//   Phase C (R0 dec_gru body, blocks [0,512)):  h_{t+1}          [t<T]
//   barrier
// ---------------------------------------------------------------------------
struct AttSm {
    float scx[4][512];
    float ctxl[512];
    float hl[512];
    float ah_l[512];
    double sml[8];
};
struct SoftSm { float red_f[256]; double red_d[256]; int red_i[256]; };
struct LogSm { float As[16][68]; float Ws[64][68]; };
struct GruSm { float Xs[16][36]; float Hs2[16][36]; float Wi[48][36]; float Wh[48][36]; };
union DecSm { AttSm a; SoftSm s; LogSm g; GruSm u; };

__global__ __launch_bounds__(256, 3) void dec_persist(
    const float* __restrict__ enc_out,
    float* __restrict__ h0buf, float* __restrict__ h1buf,
    const float* __restrict__ att_W, const float* __restrict__ att_b,
    const float* __restrict__ out_W, const float* __restrict__ out_b,
    const float* __restrict__ mlp_W, const float* __restrict__ mlp_tab,
    const float* __restrict__ Wih, const float* __restrict__ Whh,
    const float* __restrict__ bih, const float* __restrict__ bhh,
    const int* __restrict__ input_len, const int* __restrict__ target_seq,
    float* __restrict__ lgb_evn, float* __restrict__ lgb_odd,
    float* __restrict__ xbuf, float* __restrict__ nll,
    float* __restrict__ inference, int* __restrict__ bar)
{
    __shared__ DecSm sm;
    const int bid = blockIdx.x, tid = threadIdx.x;

    for (int t = 0; t <= T + 1; ++t) {
        const float* hc = (t & 1) ? h1buf : h0buf;
        float* hx = (t & 1) ? h0buf : h1buf;
        float* lgbA = (t & 1) ? lgb_odd : lgb_evn;
        const float* lgbB = (t & 1) ? lgb_evn : lgb_odd;

        // ----- Phase B' -----
        if (bid < B) {
            if (t < T) {
                const int b = bid;
                for (int i = tid; i < 128; i += 256)
                    *(float4*)&sm.a.hl[i * 4] =
                        *(const float4*)(hc + (size_t)b * 512 + i * 4);
                __syncthreads();
                {   // ah = relu(h@attW^T + att_b) (R4 proven)
                    const int q = tid & 3, rbase = tid >> 2;
#pragma unroll
                    for (int pass = 0; pass < 8; ++pass) {
                        const int jr = pass * 64 + rbase;
                        const float* wr = att_W + (size_t)jr * 512;
                        double a = 0.0;
                        for (int k = q * 4; k < 512; k += 16)
                            a += dotd(tod4(*(const float4*)&sm.a.hl[k]),
                                      tod4(*(const float4*)(wr + k)));
                        a += __shfl_xor(a, 1, 64);
                        a += __shfl_xor(a, 2, 64);
                        if (q == 0) {
                            double v = a + (double)att_b[jr];
                            if (v < 0.0) v = 0.0;
                            sm.a.ah_l[jr] = (float)v;
                        }
                    }
                }
                __syncthreads();

                const int wave = tid >> 6, lane = tid & 63;
                const int len = input_len[b];
                d4 aa1 = tod4(*(const float4*)&sm.a.ah_l[lane * 4]);
                d4 aa2 = tod4(*(const float4*)&sm.a.ah_l[256 + lane * 4]);
                double m = -INFINITY, l = 0.0;
                d4 c1 = {0,0,0,0}, c2 = {0,0,0,0};
                for (int s = wave; s < len; s += 4) {
                    const float* row = enc_out + ((size_t)s * B + b) * 512;
                    d4 e1 = tod4(*(const float4*)(row + lane * 4));
                    d4 e2 = tod4(*(const float4*)(row + 256 + lane * 4));
                    double p = dotd(e1, aa1) + dotd(e2, aa2);
#pragma unroll
                    for (int off = 32; off >= 1; off >>= 1)
                        p += __shfl_xor(p, off, 64);
                    double mn = fmax(m, p);
                    double sc = (m == mn) ? 1.0 : exp(m - mn);
                    double w = exp(p - mn);
                    l = l * sc + w;
                    c1.x = c1.x * sc + w * e1.x; c1.y = c1.y * sc + w * e1.y;
                    c1.z = c1.z * sc + w * e1.z; c1.w = c1.w * sc + w * e1.w;
                    c2.x = c2.x * sc + w * e2.x; c2.y = c2.y * sc + w * e2.y;
                    c2.z = c2.z * sc + w * e2.z; c2.w = c2.w * sc + w * e2.w;
                    m = mn;
                }
                if (lane == 0) { sm.a.sml[wave] = m; sm.a.sml[4 + wave] = l; }
                *(float4*)&sm.a.scx[wave][lane * 4] =
                    make_float4((float)c1.x, (float)c1.y, (float)c1.z, (float)c1.w);
                *(float4*)&sm.a.scx[wave][256 + lane * 4] =
                    make_float4((float)c2.x, (float)c2.y, (float)c2.z, (float)c2.w);
                __syncthreads();
                double M = fmax(fmax(sm.a.sml[0], sm.a.sml[1]),
                                fmax(sm.a.sml[2], sm.a.sml[3]));
                if (len < S) M = fmax(M, 0.0);
                double w0 = exp(sm.a.sml[0] - M), w1x = exp(sm.a.sml[1] - M);
                double w2x = exp(sm.a.sml[2] - M), w3 = exp(sm.a.sml[3] - M);
                double L = sm.a.sml[4] * w0 + sm.a.sml[5] * w1x
                         + sm.a.sml[6] * w2x + sm.a.sml[7] * w3
                         + (double)(S - len) * exp(0.0 - M);
                for (int jj = tid; jj < 512; jj += 256) {
                    double v = (double)sm.a.scx[0][jj] * w0
                             + (double)sm.a.scx[1][jj] * w1x
                             + (double)sm.a.scx[2][jj] * w2x
                             + (double)sm.a.scx[3][jj] * w3;
                    sm.a.ctxl[jj] = (float)(v / L);
                }
                __syncthreads();

                const int tok = (t == 0) ? 1 : target_seq[(t - 1) * B + b];
                const int q = tid & 3;
                const int rbase = tid >> 2;
#pragma unroll
                for (int pass = 0; pass < 8; ++pass) {
                    const int jr = pass * 64 + rbase;
                    const float* wr = mlp_W + (size_t)jr * 1024 + 512;
                    double a = 0.0;
                    for (int k = q * 4; k < 512; k += 16) {
                        a += dotd(tod4(*(const float4*)&sm.a.ctxl[k]),
                                  tod4(*(const float4*)(wr + k)));
                    }
                    a += __shfl_xor(a, 1, 64);
                    a += __shfl_xor(a, 2, 64);
                    if (q == 0)
                        xbuf[(size_t)b * 512 + jr] =
                            (float)tanh((double)mlp_tab[(size_t)tok * 512 + jr] + a);
                }
            }
        } else if (bid < 2 * B) {
            if (t >= 2) {
                const int sb = bid - B;
                const int dt = t - 2;
                const float* lg = lgbB + (size_t)sb * 512;
                const float l0 = lg[tid], l1 = lg[256 + tid];
                sm.s.red_f[tid] = fmaxf(l0, l1);
                __syncthreads();
                for (int off = 128; off > 0; off >>= 1) {
                    if (tid < off)
                        sm.s.red_f[tid] = fmaxf(sm.s.red_f[tid], sm.s.red_f[tid + off]);
                    __syncthreads();
                }
                const double mx = (double)sm.s.red_f[0];
                __syncthreads();
                const double e0 = exp((double)l0 - mx), e1 = exp((double)l1 - mx);
                sm.s.red_d[tid] = e0 + e1;
                __syncthreads();
                for (int off = 128; off > 0; off >>= 1) {
                    if (tid < off) sm.s.red_d[tid] += sm.s.red_d[tid + off];
                    __syncthreads();
                }
                const double Z = sm.s.red_d[0];
                __syncthreads();
                const float p0 = (float)(e0 / Z), p1 = (float)(e1 / Z);
                float v; int idx;
                if (p0 >= p1) { v = p0; idx = tid; } else { v = p1; idx = 256 + tid; }
                sm.s.red_f[tid] = v; sm.s.red_i[tid] = idx;
                __syncthreads();
                for (int off = 128; off > 0; off >>= 1) {
                    if (tid < off) {
                        float ov = sm.s.red_f[tid + off];
                        int oi = sm.s.red_i[tid + off];
                        if (ov > sm.s.red_f[tid] ||
                            (ov == sm.s.red_f[tid] && oi < sm.s.red_i[tid])) {
                            sm.s.red_f[tid] = ov; sm.s.red_i[tid] = oi;
                        }
                    }
                    __syncthreads();
                }
                if (tid == 0) {
                    int tg = target_seq[dt * B + sb];
                    float pt = (float)(exp((double)lg[tg] - mx) / Z);
                    pt = fmaxf(pt, 1e-10f);
                    nll[dt * B + sb] = (float)(-log((double)pt));
                    inference[dt * B + sb] = (float)sm.s.red_i[0];
                }
            }
        } else {
            if (t >= 1 && t <= T) {
                const int g = bid - 2 * B;
                const int n0 = (g & 7) * 64, m0 = (g >> 3) * 16;
                const int lane = tid & 63, wv = tid >> 6;
                const int lr = lane & 15, gk = lane >> 4;
                int am, ak, rowd[4];
                calib(lane, am, ak, rowd);

                const int arow = tid >> 4, ac4 = (tid & 15) * 4;
                float4 areg = *(const float4*)(hc + (size_t)(m0 + arow) * 512 + ac4);
                float4 wreg[4];
#pragma unroll
                for (int i = 0; i < 4; ++i) {
                    int x4 = i * 256 + tid, row = x4 >> 4, c4 = (x4 & 15) * 4;
                    wreg[i] = *(const float4*)(out_W + (size_t)(n0 + row) * 512 + c4);
                }
                *(float4*)&sm.g.As[arow][ac4] = areg;
#pragma unroll
                for (int i = 0; i < 4; ++i) {
                    int x4 = i * 256 + tid, row = x4 >> 4, c4 = (x4 & 15) * 4;
                    *(float4*)&sm.g.Ws[row][c4] = wreg[i];
                }
                __syncthreads();

                f64x4 c = {0,0,0,0};
                for (int k0 = 0; k0 < 512; k0 += 64) {
                    const bool more = (k0 + 64) < 512;
                    if (more) {
                        areg = *(const float4*)(hc + (size_t)(m0 + arow) * 512
                                                + k0 + 64 + ac4);
#pragma unroll
                        for (int i = 0; i < 4; ++i) {
                            int x4 = i * 256 + tid, row = x4 >> 4, c4 = (x4 & 15) * 4;
                            wreg[i] = *(const float4*)(out_W + (size_t)(n0 + row) * 512
                                                       + k0 + 64 + c4);
                        }
                    }
#pragma unroll
                    for (int kk = 0; kk < 16; ++kk) {
                        double a  = (double)sm.g.As[am][kk * 4 + ak];
                        double bb = (double)sm.g.Ws[wv * 16 + lr][kk * 4 + gk];
                        c = __builtin_amdgcn_mfma_f64_16x16x4f64(a, bb, c, 0, 0, 0);
                    }
                    __syncthreads();
                    if (more) {
                        *(float4*)&sm.g.As[arow][ac4] = areg;
#pragma unroll
                        for (int i = 0; i < 4; ++i) {
                            int x4 = i * 256 + tid, row = x4 >> 4, c4 = (x4 & 15) * 4;
                            *(float4*)&sm.g.Ws[row][c4] = wreg[i];
                        }
                        __syncthreads();
                    }
                }
                const int ng = n0 + wv * 16 + lr;
#pragma unroll
                for (int d = 0; d < 4; ++d)
                    lgbA[(size_t)(m0 + rowd[d]) * 512 + ng] =
                        (float)(c[d] + (double)out_b[ng]);
            }
        }

        gridbar(bar, 640);

        // ----- Phase C: decoder GRU (R0 body, blocks 0..511) -----
        if (t < T) {
            if (bid < 512) {
                const int j_l = tid & 15, b_l = tid >> 4;
                const int j0 = (bid & 31) * 16, b0 = (bid >> 5) * 16;
                const int j = j0 + j_l, b = b0 + b_l;

                double air = 0, aiz = 0, ain = 0, ahr = 0, ahz = 0, ahn = 0;
                for (int kt = 0; kt < 512; kt += 32) {
                    __syncthreads();
                    for (int idx = tid; idx < 1024; idx += 256) {
                        if (idx < 128) {
                            int row = idx >> 3, c4 = (idx & 7) * 4;
                            *(float4*)&sm.u.Xs[row][c4] =
                                *(const float4*)(xbuf + (size_t)(b0 + row) * 512 + kt + c4);
                        } else if (idx < 256) {
                            int w = idx - 128; int row = w >> 3, c4 = (w & 7) * 4;
                            *(float4*)&sm.u.Hs2[row][c4] =
                                *(const float4*)(hc + (size_t)(b0 + row) * 512 + kt + c4);
                        } else if (idx < 640) {
                            int w = idx - 256; int row = w >> 3, c4 = (w & 7) * 4;
                            int g = row >> 4, jj = row & 15;
                            *(float4*)&sm.u.Wi[row][c4] =
                                *(const float4*)(Wih + (size_t)(g * 512 + j0 + jj) * 512 + kt + c4);
                        } else {
                            int w = idx - 640; int row = w >> 3, c4 = (w & 7) * 4;
                            int g = row >> 4, jj = row & 15;
                            *(float4*)&sm.u.Wh[row][c4] =
                                *(const float4*)(Whh + (size_t)(g * 512 + j0 + jj) * 512 + kt + c4);
                        }
                    }
                    __syncthreads();
#pragma unroll
                    for (int kk = 0; kk < 32; kk += 4) {
                        d4 xv = tod4(*(const float4*)&sm.u.Xs[b_l][kk]);
                        d4 hv = tod4(*(const float4*)&sm.u.Hs2[b_l][kk]);
                        air += dotd(xv, tod4(*(const float4*)&sm.u.Wi[j_l][kk]));
                        aiz += dotd(xv, tod4(*(const float4*)&sm.u.Wi[16 + j_l][kk]));
                        ain += dotd(xv, tod4(*(const float4*)&sm.u.Wi[32 + j_l][kk]));
                        ahr += dotd(hv, tod4(*(const float4*)&sm.u.Wh[j_l][kk]));
                        ahz += dotd(hv, tod4(*(const float4*)&sm.u.Wh[16 + j_l][kk]));
                        ahn += dotd(hv, tod4(*(const float4*)&sm.u.Wh[32 + j_l][kk]));
                    }
                }

                double r = sigd(air + (double)bih[j] + ahr + (double)bhh[j]);
                double z = sigd(aiz + (double)bih[512 + j] + ahz + (double)bhh[512 + j]);
                double n = tanh(ain + (double)bih[1024 + j]
                                + r * (ahn + (double)bhh[1024 + j]));
                float hold = hc[(size_t)b * 512 + j];
                hx[(size_t)b * 512 + j] = (float)((1.0 - z) * n + z * (double)hold);
            }
            gridbar(bar, 640);
        }
    }
}

// ---------------------------------------------------------------------------
// Final reduction (proven).
// ---------------------------------------------------------------------------
__global__ __launch_bounds__(256) void finalize_k(
    const float* __restrict__ nll, const float* __restrict__ inference,
    const int* __restrict__ target, float* __restrict__ out3)
{
    const int tid = threadIdx.x;
    int wrong = 0;
    double match = 0.0;
    const int b = tid;
    for (int t = 0; t < T; ++t) {
        float inf = inference[t * B + b];
        float tg = (float)target[t * B + b];
        bool ok = (inf == tg);
        match += ok ? 1.0 : 0.0;
        wrong |= !ok;
    }
    double lsum = 0.0;
    for (int i = tid; i < T * B; i += 256) lsum += (double)nll[i];

    __shared__ double sl[256], sm_[256], sa[256];
    sl[tid] = lsum; sm_[tid] = match; sa[tid] = wrong ? 0.0 : 1.0;
    __syncthreads();
    for (int off = 128; off > 0; off >>= 1) {
        if (tid < off) {
            sl[tid] += sl[tid + off];
            sm_[tid] += sm_[tid + off];
            sa[tid] += sa[tid + off];
        }
        __syncthreads();
    }
    if (tid == 0) {
        out3[0] = (float)(sl[0] / (double)(T * B));
        out3[1] = (float)(sa[0] / (double)B);
        out3[2] = (float)(sm_[0] / (double)(T * B));
    }
}

// ---------------------------------------------------------------------------
extern "C" void kernel_launch(void* const* d_in, const int* in_sizes, int n_in,
                              void* d_out, int out_size, void* d_ws, size_t ws_size,
                              hipStream_t stream)
{
    const int*   input_seq  = (const int*)d_in[0];
    const int*   input_len  = (const int*)d_in[1];
    const int*   target_seq = (const int*)d_in[2];
    const float* enc_embed  = (const float*)d_in[3];
    const float* enc_Wih    = (const float*)d_in[4];
    const float* enc_Whh    = (const float*)d_in[5];
    const float* enc_bih    = (const float*)d_in[6];
    const float* enc_bhh    = (const float*)d_in[7];
    const float* att_W      = (const float*)d_in[8];
    const float* att_b      = (const float*)d_in[9];
    const float* dec_embed  = (const float*)d_in[10];
    const float* dec_Wih    = (const float*)d_in[11];
    const float* dec_Whh    = (const float*)d_in[12];
    const float* dec_bih    = (const float*)d_in[13];
    const float* dec_bhh    = (const float*)d_in[14];
    const float* mlp_W      = (const float*)d_in[15];
    const float* mlp_b      = (const float*)d_in[16];
    const float* out_W      = (const float*)d_in[17];
    const float* out_b      = (const float*)d_in[18];

    float* out = (float*)d_out;   // [inference (T*B) | loss | acc | all_acc]

    float* gi_tab  = (float*)d_ws;                   // (V, 3H)
    float* mlp_tab = gi_tab + (size_t)VOC * G3;      // (V, H)
    float* h0      = mlp_tab + (size_t)VOC * Hh;     // (B, H)
    float* h1      = h0 + (size_t)B * Hh;
    float* lgb_odd = h1 + (size_t)B * Hh;            // (B, H)
    float* xb      = lgb_odd + (size_t)B * Hh;
    float* lgb_evn = xb + (size_t)B * Hh;            // (B, H)
    float* nllb    = lgb_evn + (size_t)B * Hh;       // (T, B)
    float* enc_out = nllb + (size_t)T * B;           // (S, B, H) ~100 MB
    int*   bar     = (int*)(enc_out + (size_t)S * B * Hh);   // 2 ints
    // ws capacity verified >= 118.17 MB by round-2 probe; this ends ~111.9 MB.

    hipMemsetAsync(h0, 0, (size_t)B * Hh * sizeof(float), stream);
    hipMemsetAsync(bar, 0, 2 * sizeof(int), stream);

    // Precompute tables:
    gemm_at<<<dim3(48, 16), 256, 0, stream>>>(
        enc_embed, enc_Wih, 512, 0, enc_bih, gi_tab, G3);
    gemm_at<<<dim3(16, 16), 256, 0, stream>>>(
        dec_embed, mlp_W, 1024, 0, mlp_b, mlp_tab, Hh);

    // Encoder scan: ONE persistent launch (final h lands in h0).
    enc_persist<<<dim3(256), 512, 0, stream>>>(
        h0, h1, gi_tab, input_seq, input_len, enc_Whh, enc_bhh, enc_out, bar);

    // Decoder scan: ONE persistent launch.
    dec_persist<<<dim3(640), 256, 0, stream>>>(
        enc_out, h0, h1, att_W, att_b, out_W, out_b, mlp_W, mlp_tab,
        dec_Wih, dec_Whh, dec_bih, dec_bhh, input_len, target_seq,
        lgb_evn, lgb_odd, xb, nllb, out, bar);

    finalize_k<<<dim3(1), 256, 0, stream>>>(nllb, out, target_seq, out + (size_t)T * B);
}

// Round 6
// 34866.541 us; speedup vs baseline: 2.5991x; 2.5991x over previous
//
#include <hip/hip_runtime.h>
#include <math.h>

// Problem constants
#define B 256
#define Hh 512
#define S 200
#define T 200
#define VOC 512
#define G3 1536
#define PAD 36

// fp64 helpers: inner-product math in double, tensor boundaries quantized fp32.
struct d4 { double x, y, z, w; };
__device__ __forceinline__ d4 tod4(const float4 a) {
    d4 r; r.x = a.x; r.y = a.y; r.z = a.z; r.w = a.w; return r;
}
__device__ __forceinline__ double dotd(const d4& a, const d4& b) {
    return a.x * b.x + a.y * b.y + a.z * b.z + a.w * b.w;
}
__device__ __forceinline__ double sigd(double x) { return 1.0 / (1.0 + exp(-x)); }

// ---------------------------------------------------------------------------
// Table-precompute GEMM (R0 proven).
// ---------------------------------------------------------------------------
__global__ __launch_bounds__(256) void gemm_at(
    const float* __restrict__ A,
    const float* __restrict__ W, int ldw, int woff,
    const float* __restrict__ bias,
    float* __restrict__ C, int ldc)
{
    __shared__ float As[32][PAD];
    __shared__ float Ws[32][PAD];
    const int tid = threadIdx.x;
    const int tx = tid & 15, ty = tid >> 4;
    const int j0 = blockIdx.x * 32, m0 = blockIdx.y * 32;
    const int lr = tid >> 3, lc = (tid & 7) * 4;

    double acc00 = 0.0, acc01 = 0.0, acc10 = 0.0, acc11 = 0.0;

    for (int k0 = 0; k0 < 512; k0 += 32) {
        float4 av = *(const float4*)(A + (size_t)(m0 + lr) * 512 + k0 + lc);
        float4 wv = *(const float4*)(W + (size_t)(j0 + lr) * ldw + woff + k0 + lc);
        __syncthreads();
        *(float4*)&As[lr][lc] = av;
        *(float4*)&Ws[lr][lc] = wv;
        __syncthreads();
#pragma unroll
        for (int kk = 0; kk < 32; kk += 4) {
            d4 a0 = tod4(*(const float4*)&As[ty][kk]);
            d4 a1 = tod4(*(const float4*)&As[ty + 16][kk]);
            d4 b0 = tod4(*(const float4*)&Ws[tx][kk]);
            d4 b1 = tod4(*(const float4*)&Ws[tx + 16][kk]);
            acc00 += dotd(a0, b0);
            acc01 += dotd(a0, b1);
            acc10 += dotd(a1, b0);
            acc11 += dotd(a1, b1);
        }
    }
    const int ms[2] = { m0 + ty, m0 + ty + 16 };
    const int js[2] = { j0 + tx, j0 + tx + 16 };
    double accs[2][2] = { { acc00, acc01 }, { acc10, acc11 } };
#pragma unroll
    for (int mi = 0; mi < 2; ++mi)
#pragma unroll
        for (int ji = 0; ji < 2; ++ji) {
            int m = ms[mi], j = js[ji];
            C[(size_t)m * ldc + j] = (float)(accs[mi][ji] + (double)bias[j]);
        }
}

// ---------------------------------------------------------------------------
// Encoder GRU step (R0 proven, verbatim). 512 thr, grid (32, 8).
// ---------------------------------------------------------------------------
__global__ __launch_bounds__(512) void enc_step(
    const float* __restrict__ h_in, float* __restrict__ h_out,
    const float* __restrict__ gi_tab, const int* __restrict__ iseq,
    const int* __restrict__ ilen, const float* __restrict__ Whh,
    const float* __restrict__ bhh, int s, float* __restrict__ enc_out)
{
    __shared__ float Hs[32][68];
    __shared__ float Ws[48][68];
    const int tid = threadIdx.x;
    const int j_l = tid & 15, b_l = tid >> 4;
    const int j0 = blockIdx.x * 16, b0 = blockIdx.y * 32;
    const int j = j0 + j_l, b = b0 + b_l;

    int ml = 0;
    for (int i = 0; i < 32; ++i) ml = max(ml, ilen[b0 + i]);
    if (s >= ml) {
        h_out[(size_t)b * 512 + j] = h_in[(size_t)b * 512 + j];
        enc_out[((size_t)s * B + b) * 512 + j] = 0.f;
        return;
    }

    double ar = 0.0, az = 0.0, an = 0.0;
    for (int kt = 0; kt < 512; kt += 64) {
        __syncthreads();
        {
            int row = tid >> 4, c4 = (tid & 15) * 4;
            *(float4*)&Hs[row][c4] =
                *(const float4*)(h_in + (size_t)(b0 + row) * 512 + kt + c4);
            for (int idx = tid; idx < 768; idx += 512) {
                int r = idx >> 4, cc = (idx & 15) * 4;
                int g = r >> 4, jj = r & 15;
                *(float4*)&Ws[r][cc] =
                    *(const float4*)(Whh + (size_t)(g * 512 + j0 + jj) * 512 + kt + cc);
            }
        }
        __syncthreads();
#pragma unroll
        for (int kk = 0; kk < 64; kk += 4) {
            d4 hv = tod4(*(const float4*)&Hs[b_l][kk]);
            ar += dotd(hv, tod4(*(const float4*)&Ws[j_l][kk]));
            az += dotd(hv, tod4(*(const float4*)&Ws[16 + j_l][kk]));
            an += dotd(hv, tod4(*(const float4*)&Ws[32 + j_l][kk]));
        }
    }

    float hold = h_in[(size_t)b * 512 + j];
    float hnew = hold;
    if (s < ilen[b]) {
        int tok = iseq[s * B + b];
        const float* gi = gi_tab + (size_t)tok * G3;
        double r = sigd((double)gi[j] + ar + (double)bhh[j]);
        double z = sigd((double)gi[512 + j] + az + (double)bhh[512 + j]);
        double n = tanh((double)gi[1024 + j] + r * (an + (double)bhh[1024 + j]));
        hnew = (float)((1.0 - z) * n + z * (double)hold);
        enc_out[((size_t)s * B + b) * 512 + j] = hnew;
    } else {
        enc_out[((size_t)s * B + b) * 512 + j] = 0.f;
    }
    h_out[(size_t)b * 512 + j] = hnew;
}

// ---------------------------------------------------------------------------
// proj (R0 proven, verbatim): dual GEMM [att_W; out_W], 512 thr, grid (32,8).
// ---------------------------------------------------------------------------
__global__ __launch_bounds__(512) void proj(
    const float* __restrict__ h,
    const float* __restrict__ att_W, const float* __restrict__ att_b,
    const float* __restrict__ out_W, const float* __restrict__ out_b,
    float* __restrict__ ah, float* __restrict__ logits, int t)
{
    __shared__ float As[32][68];
    __shared__ float Ws[32][68];
    const int tid = threadIdx.x;
    const int tx = tid & 15, ty = tid >> 4;
    const int R0 = blockIdx.x * 32, m0 = blockIdx.y * 32;
    const bool is_att = (R0 < 512);
    if (is_att && t >= T) return;   // block-uniform

    double a0 = 0.0, a1 = 0.0;
    for (int kt = 0; kt < 512; kt += 64) {
        __syncthreads();
        {
            int row = tid >> 4, c4 = (tid & 15) * 4;
            *(float4*)&As[row][c4] =
                *(const float4*)(h + (size_t)(m0 + row) * 512 + kt + c4);
            int R = R0 + row;
            const float* ws = is_att ? (att_W + (size_t)R * 512)
                                     : (out_W + (size_t)(R - 512) * 512);
            *(float4*)&Ws[row][c4] = *(const float4*)(ws + kt + c4);
        }
        __syncthreads();
#pragma unroll
        for (int kk = 0; kk < 64; kk += 4) {
            d4 av = tod4(*(const float4*)&As[ty][kk]);
            a0 += dotd(av, tod4(*(const float4*)&Ws[tx][kk]));
            a1 += dotd(av, tod4(*(const float4*)&Ws[16 + tx][kk]));
        }
    }

    const int m = m0 + ty;
    const int Ra = R0 + tx, Rb = R0 + tx + 16;
    if (is_att) {
        double v0 = a0 + (double)att_b[Ra]; if (v0 < 0.0) v0 = 0.0;
        double v1 = a1 + (double)att_b[Rb]; if (v1 < 0.0) v1 = 0.0;
        ah[(size_t)m * 512 + Ra] = (float)v0;
        ah[(size_t)m * 512 + Rb] = (float)v1;
    } else {
        logits[(size_t)m * 512 + (Ra - 512)] = (float)(a0 + (double)out_b[Ra - 512]);
        logits[(size_t)m * 512 + (Rb - 512)] = (float)(a1 + (double)out_b[Rb - 512]);
    }
}

// ---------------------------------------------------------------------------
// attn_ctx: latency-parallel attention (replaces R0's serial online-softmax).
//  blocks [0,256):   per-b: e[s] via R0's exact dot (independent iterations),
//                    parallel max, PARALLEL exp, serial-deterministic L,
//                    per-j coalesced f64 ctx accumulation, ctx fp32 out.
//  blocks [256,512): softmax/argmax/nll of logits (R0 verbatim, step t-1).
// ---------------------------------------------------------------------------
__global__ __launch_bounds__(256) void attn_ctx(
    const float* __restrict__ enc_out, const float* __restrict__ ah,
    const int* __restrict__ input_len, const int* __restrict__ target_seq,
    const float* __restrict__ logits, int t,
    float* __restrict__ ctxb, float* __restrict__ nll,
    float* __restrict__ inference)
{
    const int bid = blockIdx.x, tid = threadIdx.x;

    if (bid < B) {
        if (t >= T) return;
        __shared__ double e_w[200];
        __shared__ double red[256];
        const int b = bid;
        const int wave = tid >> 6, lane = tid & 63;
        const int len = input_len[b];
        const float* ahb = ah + (size_t)b * 512;
        d4 aa1 = tod4(*(const float4*)(ahb + lane * 4));
        d4 aa2 = tod4(*(const float4*)(ahb + 256 + lane * 4));

        // pass 1: e[s] (same bitwise dot+reduce as R0, but no serial chain)
        for (int s = wave; s < len; s += 4) {
            const float* row = enc_out + ((size_t)s * B + b) * 512;
            d4 e1 = tod4(*(const float4*)(row + lane * 4));
            d4 e2 = tod4(*(const float4*)(row + 256 + lane * 4));
            double p = dotd(e1, aa1) + dotd(e2, aa2);
#pragma unroll
            for (int off = 32; off >= 1; off >>= 1) p += __shfl_xor(p, off, 64);
            if (lane == 0) e_w[s] = p;
        }
        __syncthreads();

        // block max
        double mloc = -INFINITY;
        for (int s2 = tid; s2 < len; s2 += 256) mloc = fmax(mloc, e_w[s2]);
        red[tid] = mloc;
        __syncthreads();
        for (int off = 128; off > 0; off >>= 1) {
            if (tid < off) red[tid] = fmax(red[tid], red[tid + off]);
            __syncthreads();
        }
        double M = red[0];
        if (len < S) M = fmax(M, 0.0);   // zero rows participate in softmax
        __syncthreads();

        // parallel exp
        if (tid < len) e_w[tid] = exp(e_w[tid] - M);
        __syncthreads();

        // deterministic L (ascending s) + analytic zero tail
        if (tid == 0) {
            double acc = 0.0;
            for (int s2 = 0; s2 < len; ++s2) acc += e_w[s2];
            acc += (double)(S - len) * exp(0.0 - M);
            red[0] = acc;
        }
        __syncthreads();
        const double L = red[0];

        // ctx: per-j f64 accumulation, coalesced rows, no cross-lane ops
        double acc0 = 0.0, acc1 = 0.0;
        for (int s2 = 0; s2 < len; ++s2) {
            const float* row = enc_out + ((size_t)s2 * B + b) * 512;
            const double w = e_w[s2];
            acc0 += w * (double)row[tid];
            acc1 += w * (double)row[tid + 256];
        }
        ctxb[(size_t)b * 512 + tid]       = (float)(acc0 / L);
        ctxb[(size_t)b * 512 + tid + 256] = (float)(acc1 / L);
    } else {
        if (t < 1) return;
        __shared__ float red_f[256];
        __shared__ double red_d[256];
        __shared__ int red_i[256];
        const int sb = bid - B;
        const float* lg = logits + (size_t)sb * 512;
        const float l0 = lg[tid], l1 = lg[256 + tid];
        red_f[tid] = fmaxf(l0, l1);
        __syncthreads();
        for (int off = 128; off > 0; off >>= 1) {
            if (tid < off) red_f[tid] = fmaxf(red_f[tid], red_f[tid + off]);
            __syncthreads();
        }
        const double mx = (double)red_f[0];
        __syncthreads();
        const double e0 = exp((double)l0 - mx), e1 = exp((double)l1 - mx);
        red_d[tid] = e0 + e1;
        __syncthreads();
        for (int off = 128; off > 0; off >>= 1) {
            if (tid < off) red_d[tid] += red_d[tid + off];
            __syncthreads();
        }
        const double Z = red_d[0];
        __syncthreads();
        const float p0 = (float)(e0 / Z), p1 = (float)(e1 / Z);
        float v; int idx;
        if (p0 >= p1) { v = p0; idx = tid; } else { v = p1; idx = 256 + tid; }
        red_f[tid] = v; red_i[tid] = idx;
        __syncthreads();
        for (int off = 128; off > 0; off >>= 1) {
            if (tid < off) {
                float ov = red_f[tid + off]; int oi = red_i[tid + off];
                if (ov > red_f[tid] || (ov == red_f[tid] && oi < red_i[tid])) {
                    red_f[tid] = ov; red_i[tid] = oi;
                }
            }
            __syncthreads();
        }
        if (tid == 0) {
            int tg = target_seq[(t - 1) * B + sb];
            float pt = (float)(exp((double)lg[tg] - mx) / Z);
            pt = fmaxf(pt, 1e-10f);
            nll[(t - 1) * B + sb] = (float)(-log((double)pt));
            inference[(t - 1) * B + sb] = (float)red_i[0];
        }
    }
}

// ---------------------------------------------------------------------------
// xgemm: x = tanh(mlp_tab[tok] + ctx @ mlpW2^T). Clone of the proven proj
// tile (512 thr, 32x32 tile, k-chunk 64); weights read once per j-tile
// instead of once per b-block. Grid (16 j-tiles, 8 b-tiles).
// ---------------------------------------------------------------------------
__global__ __launch_bounds__(512) void xgemm(
    const float* __restrict__ ctxb, const float* __restrict__ mlp_W,
    const float* __restrict__ mlp_tab, const int* __restrict__ target_seq,
    int t, float* __restrict__ xb)
{
    __shared__ float As[32][68];
    __shared__ float Ws[32][68];
    const int tid = threadIdx.x;
    const int tx = tid & 15, ty = tid >> 4;
    const int j0 = blockIdx.x * 32, m0 = blockIdx.y * 32;

    double a0 = 0.0, a1 = 0.0;
    for (int kt = 0; kt < 512; kt += 64) {
        __syncthreads();
        {
            int row = tid >> 4, c4 = (tid & 15) * 4;
            *(float4*)&As[row][c4] =
                *(const float4*)(ctxb + (size_t)(m0 + row) * 512 + kt + c4);
            *(float4*)&Ws[row][c4] =
                *(const float4*)(mlp_W + (size_t)(j0 + row) * 1024 + 512 + kt + c4);
        }
        __syncthreads();
#pragma unroll
        for (int kk = 0; kk < 64; kk += 4) {
            d4 av = tod4(*(const float4*)&As[ty][kk]);
            a0 += dotd(av, tod4(*(const float4*)&Ws[tx][kk]));
            a1 += dotd(av, tod4(*(const float4*)&Ws[16 + tx][kk]));
        }
    }

    const int m = m0 + ty;
    const int tok = (t == 0) ? 1 : target_seq[(t - 1) * B + m];
    const int ja = j0 + tx, jb = j0 + tx + 16;
    xb[(size_t)m * 512 + ja] =
        (float)tanh((double)mlp_tab[(size_t)tok * 512 + ja] + a0);
    xb[(size_t)m * 512 + jb] =
        (float)tanh((double)mlp_tab[(size_t)tok * 512 + jb] + a1);
}

// ---------------------------------------------------------------------------
// Decoder GRU (R0 proven, verbatim). Grid (32,16) x 256 thr.
// ---------------------------------------------------------------------------
__global__ __launch_bounds__(256) void dec_gru(
    const float* __restrict__ x, const float* __restrict__ h_in,
    const float* __restrict__ Wih, const float* __restrict__ Whh,
    const float* __restrict__ bih, const float* __restrict__ bhh,
    float* __restrict__ h_out)
{
    __shared__ float Xs[16][36];
    __shared__ float Hs2[16][36];
    __shared__ float Wi[48][36];
    __shared__ float Wh[48][36];
    const int tid = threadIdx.x;
    const int j_l = tid & 15, b_l = tid >> 4;
    const int j0 = blockIdx.x * 16, b0 = blockIdx.y * 16;
    const int j = j0 + j_l, b = b0 + b_l;

    double air = 0, aiz = 0, ain = 0, ahr = 0, ahz = 0, ahn = 0;
    for (int kt = 0; kt < 512; kt += 32) {
        __syncthreads();
        for (int idx = tid; idx < 1024; idx += 256) {
            if (idx < 128) {
                int row = idx >> 3, c4 = (idx & 7) * 4;
                *(float4*)&Xs[row][c4] =
                    *(const float4*)(x + (size_t)(b0 + row) * 512 + kt + c4);
            } else if (idx < 256) {
                int w = idx - 128; int row = w >> 3, c4 = (w & 7) * 4;
                *(float4*)&Hs2[row][c4] =
                    *(const float4*)(h_in + (size_t)(b0 + row) * 512 + kt + c4);
            } else if (idx < 640) {
                int w = idx - 256; int row = w >> 3, c4 = (w & 7) * 4;
                int g = row >> 4, jj = row & 15;
                *(float4*)&Wi[row][c4] =
                    *(const float4*)(Wih + (size_t)(g * 512 + j0 + jj) * 512 + kt + c4);
            } else {
                int w = idx - 640; int row = w >> 3, c4 = (w & 7) * 4;
                int g = row >> 4, jj = row & 15;
                *(float4*)&Wh[row][c4] =
                    *(const float4*)(Whh + (size_t)(g * 512 + j0 + jj) * 512 + kt + c4);
            }
        }
        __syncthreads();
#pragma unroll
        for (int kk = 0; kk < 32; kk += 4) {
            d4 xv = tod4(*(const float4*)&Xs[b_l][kk]);
            d4 hv = tod4(*(const float4*)&Hs2[b_l][kk]);
            air += dotd(xv, tod4(*(const float4*)&Wi[j_l][kk]));
            aiz += dotd(xv, tod4(*(const float4*)&Wi[16 + j_l][kk]));
            ain += dotd(xv, tod4(*(const float4*)&Wi[32 + j_l][kk]));
            ahr += dotd(hv, tod4(*(const float4*)&Wh[j_l][kk]));
            ahz += dotd(hv, tod4(*(const float4*)&Wh[16 + j_l][kk]));
            ahn += dotd(hv, tod4(*(const float4*)&Wh[32 + j_l][kk]));
        }
    }

    double r = sigd(air + (double)bih[j] + ahr + (double)bhh[j]);
    double z = sigd(aiz + (double)bih[512 + j] + ahz + (double)bhh[512 + j]);
    double n = tanh(ain + (double)bih[1024 + j] + r * (ahn + (double)bhh[1024 + j]));
    float hold = h_in[(size_t)b * 512 + j];
    h_out[(size_t)b * 512 + j] = (float)((1.0 - z) * n + z * (double)hold);
}

// ---------------------------------------------------------------------------
// Final reduction (R0 proven).
// ---------------------------------------------------------------------------
__global__ __launch_bounds__(256) void finalize_k(
    const float* __restrict__ nll, const float* __restrict__ inference,
    const int* __restrict__ target, float* __restrict__ out3)
{
    const int tid = threadIdx.x;
    int wrong = 0;
    double match = 0.0;
    const int b = tid;
    for (int t = 0; t < T; ++t) {
        float inf = inference[t * B + b];
        float tg = (float)target[t * B + b];
        bool ok = (inf == tg);
        match += ok ? 1.0 : 0.0;
        wrong |= !ok;
    }
    double lsum = 0.0;
    for (int i = tid; i < T * B; i += 256) lsum += (double)nll[i];

    __shared__ double sl[256], sm_[256], sa[256];
    sl[tid] = lsum; sm_[tid] = match; sa[tid] = wrong ? 0.0 : 1.0;
    __syncthreads();
    for (int off = 128; off > 0; off >>= 1) {
        if (tid < off) {
            sl[tid] += sl[tid + off];
            sm_[tid] += sm_[tid + off];
            sa[tid] += sa[tid + off];
        }
        __syncthreads();
    }
    if (tid == 0) {
        out3[0] = (float)(sl[0] / (double)(T * B));
        out3[1] = (float)(sa[0] / (double)B);
        out3[2] = (float)(sm_[0] / (double)(T * B));
    }
}

// ---------------------------------------------------------------------------
extern "C" void kernel_launch(void* const* d_in, const int* in_sizes, int n_in,
                              void* d_out, int out_size, void* d_ws, size_t ws_size,
                              hipStream_t stream)
{
    const int*   input_seq  = (const int*)d_in[0];
    const int*   input_len  = (const int*)d_in[1];
    const int*   target_seq = (const int*)d_in[2];
    const float* enc_embed  = (const float*)d_in[3];
    const float* enc_Wih    = (const float*)d_in[4];
    const float* enc_Whh    = (const float*)d_in[5];
    const float* enc_bih    = (const float*)d_in[6];
    const float* enc_bhh    = (const float*)d_in[7];
    const float* att_W      = (const float*)d_in[8];
    const float* att_b      = (const float*)d_in[9];
    const float* dec_embed  = (const float*)d_in[10];
    const float* dec_Wih    = (const float*)d_in[11];
    const float* dec_Whh    = (const float*)d_in[12];
    const float* dec_bih    = (const float*)d_in[13];
    const float* dec_bhh    = (const float*)d_in[14];
    const float* mlp_W      = (const float*)d_in[15];
    const float* mlp_b      = (const float*)d_in[16];
    const float* out_W      = (const float*)d_in[17];
    const float* out_b      = (const float*)d_in[18];

    float* out = (float*)d_out;   // [inference (T*B) | loss | acc | all_acc]

    float* gi_tab  = (float*)d_ws;                   // (V, 3H)
    float* mlp_tab = gi_tab + (size_t)VOC * G3;      // (V, H)
    float* h0      = mlp_tab + (size_t)VOC * Hh;     // (B, H)
    float* h1      = h0 + (size_t)B * Hh;
    float* ahb     = h1 + (size_t)B * Hh;
    float* xb      = ahb + (size_t)B * Hh;
    float* lgb     = xb + (size_t)B * Hh;
    float* nllb    = lgb + (size_t)B * Hh;           // (T, B)
    float* enc_out = nllb + (size_t)T * B;           // (S, B, H) ~100 MB
    float* ctxb    = enc_out + (size_t)S * B * Hh;   // (B, H) — end ~112.4 MB,
    // ws capacity verified >= 118.17 MB by the round-2 probe.

    hipMemsetAsync(h0, 0, (size_t)B * Hh * sizeof(float), stream);

    // Precompute tables:
    gemm_at<<<dim3(48, 16), 256, 0, stream>>>(
        enc_embed, enc_Wih, 512, 0, enc_bih, gi_tab, G3);
    gemm_at<<<dim3(16, 16), 256, 0, stream>>>(
        dec_embed, mlp_W, 1024, 0, mlp_b, mlp_tab, Hh);

    // Encoder scan (final h lands in h0: s=199 odd writes h0)
    for (int s = 0; s < S; ++s) {
        const float* hc = (s & 1) ? h1 : h0;
        float* hx = (s & 1) ? h0 : h1;
        enc_step<<<dim3(32, 8), 512, 0, stream>>>(
            hc, hx, gi_tab, input_seq, input_len, enc_Whh, enc_bhh, s, enc_out);
    }

    // Decoder scan: t = 0..T; at t==T only logits(h_T) + softmax(T-1) remain.
    for (int t = 0; t <= T; ++t) {
        const float* hc = (t & 1) ? h1 : h0;
        float* hx = (t & 1) ? h0 : h1;
        proj<<<dim3(32, 8), 512, 0, stream>>>(
            hc, att_W, att_b, out_W, out_b, ahb, lgb, t);
        attn_ctx<<<dim3(2 * B), 256, 0, stream>>>(
            enc_out, ahb, input_len, target_seq, lgb, t, ctxb, nllb, out);
        if (t < T) {
            xgemm<<<dim3(16, 8), 512, 0, stream>>>(
                ctxb, mlp_W, mlp_tab, target_seq, t, xb);
            dec_gru<<<dim3(32, 16), 256, 0, stream>>>(
                xb, hc, dec_Wih, dec_Whh, dec_bih, dec_bhh, hx);
        }
    }

    finalize_k<<<dim3(1), 256, 0, stream>>>(nllb, out, target_seq, out + (size_t)T * B);
}